// Round 6
// baseline (515.124 us; speedup 1.0000x reference)
//
#include <hip/hip_runtime.h>
#include <math.h>

// Problem constants
#define BB 4
#define NN 1000
#define TT 8
#define FF 64
#define HH 64
#define NHEADS 4
#define EE 16000
#define E2 17000          // EE + NN self-loops (EXACT per-graph edge total)
#define GG (BB*TT)        // 32 graphs
#define GN (GG*NN)        // 32000 (graph,node) pairs
#define NROWS (BB*NN)     // 4000 GRU rows

// ---------------- helpers ----------------
__device__ __forceinline__ float sigmoidf_(float x) {
    return 1.f / (1.f + __expf(-x));
}
__device__ __forceinline__ float tanhf_(float x) {
    x = fminf(fmaxf(x, -15.f), 15.f);
    float e = __expf(2.f * x);
    return (e - 1.f) / (e + 1.f);
}
__device__ __forceinline__ float leaky_(float x) {
    return (x > 0.f) ? x : 0.2f * x;
}

// ---------------- CSR build ----------------
__global__ void count_edges(const int* __restrict__ ei, int* __restrict__ counts) {
    int g = blockIdx.y;
    int e = blockIdx.x * 256 + threadIdx.x;
    if (e >= E2) return;
    int dst;
    if (e < EE) dst = ei[(size_t)g * 2 * EE + EE + e];
    else        dst = e - EE;   // self-loop
    atomicAdd(&counts[g * NN + dst], 1);
}

// Per-graph scan: each graph owns csr region [g*E2, (g+1)*E2); only a
// 1000-element scan per graph is needed. One 256-thread block per graph.
__global__ __launch_bounds__(256) void scan_offsets_pg(const int* __restrict__ counts,
                                                       int* __restrict__ offs) {
    __shared__ int tot[256];
    int g = blockIdx.x;
    int tid = threadIdx.x;
    int base = tid * 4;
    int c0 = 0, c1 = 0, c2 = 0, c3 = 0;
    if (base < NN) {
        int4 v = *(const int4*)(counts + (size_t)g * NN + base);  // 16B aligned (NN%4==0)
        c0 = v.x; c1 = v.y; c2 = v.z; c3 = v.w;
    }
    int s = c0 + c1 + c2 + c3;
    tot[tid] = s;
    __syncthreads();
    // Hillis-Steele inclusive scan over 256 partials
    for (int off = 1; off < 256; off <<= 1) {
        int y = (tid >= off) ? tot[tid - off] : 0;
        __syncthreads();
        tot[tid] += y;
        __syncthreads();
    }
    int run = g * E2 + tot[tid] - s;  // exclusive prefix + graph base
    if (base < NN) {
        int4 o;
        o.x = run; run += c0;
        o.y = run; run += c1;
        o.z = run; run += c2;
        o.w = run;
        *(int4*)(offs + (size_t)g * NN + base) = o;
    }
    if (g == 0 && tid == 0) offs[GN] = GG * E2;
}

__global__ void scatter_edges(const int* __restrict__ ei, const int* __restrict__ offs,
                              int* __restrict__ cursor, int* __restrict__ csr) {
    int g = blockIdx.y;
    int e = blockIdx.x * 256 + threadIdx.x;
    if (e >= E2) return;
    int src, dst;
    if (e < EE) {
        src = ei[(size_t)g * 2 * EE + e];
        dst = ei[(size_t)g * 2 * EE + EE + e];
    } else {
        src = dst = e - EE;
    }
    int i = g * NN + dst;
    int pos = offs[i] + atomicAdd(&cursor[i], 1);
    csr[pos] = src;
}

// ---------------- W transpose prep: Wt[col][f] = W[f][col] ----------------
__global__ void transpose_w(const float* __restrict__ W1, const float* __restrict__ W2,
                            float* __restrict__ Wt1, float* __restrict__ Wt2) {
    int f = blockIdx.x;      // 0..63
    int c = threadIdx.x;     // 0..255
    Wt1[(size_t)c * 64 + f] = W1[(size_t)f * 256 + c];
    Wt2[(size_t)c * 64 + f] = W2[(size_t)f * 256 + c];
}

// ---------------- GAT linear v4 ----------------
// W forced register-resident: __launch_bounds__(256,4) lifts the VGPR cap
// (bare (256) made the compiler cap at 44 VGPR and re-load W per use — R5
// regression), and 16 NAMED float4s defeat array demotion. ROWS=20 amortizes
// the one-time W load; dual partial accumulators per row for FMA-chain ILP.
#define DOT4_(acc, xv, wv)                      \
    acc = fmaf((xv).x, (wv).x, acc);            \
    acc = fmaf((xv).y, (wv).y, acc);            \
    acc = fmaf((xv).z, (wv).z, acc);            \
    acc = fmaf((xv).w, (wv).w, acc);

#define GAT_STEP(i, accA, accB)                 \
    {                                           \
        float4 a4 = ((const float4*)xa)[i];     \
        float4 b4 = ((const float4*)xb)[i];     \
        DOT4_(accA, a4, w##i);                  \
        DOT4_(accB, b4, w##i);                  \
    }

template <int MODE>
__global__ __launch_bounds__(256, 4) void gat_linear(
    const float* __restrict__ in, const float* __restrict__ Wt,
    const float* __restrict__ att_s, const float* __restrict__ att_d,
    float* __restrict__ hlin, float* __restrict__ asrc, float* __restrict__ adst) {
    const int ROWS = 20;
    const int CH = NN / ROWS;  // 50 -> 1600 blocks
    int g = blockIdx.x / CH;
    int n0 = (blockIdx.x % CH) * ROWS;
    int tid = threadIdx.x;
    const float4* wp = (const float4*)(Wt + (size_t)tid * 64);
    float4 w0 = wp[0],  w1 = wp[1],  w2 = wp[2],  w3 = wp[3];
    float4 w4 = wp[4],  w5 = wp[5],  w6 = wp[6],  w7 = wp[7];
    float4 w8 = wp[8],  w9 = wp[9],  w10 = wp[10], w11 = wp[11];
    float4 w12 = wp[12], w13 = wp[13], w14 = wp[14], w15 = wp[15];
    int head = tid >> 6, lane = tid & 63;
    float as = att_s[head * HH + lane];
    float ad = att_d[head * HH + lane];
    int b = g / TT, t = g % TT;
    for (int rr = 0; rr < ROWS; rr += 2) {
        int na = n0 + rr, nb = na + 1;
        const float *xa, *xb;
        if (MODE == 0) {
            xa = in + (((size_t)(b * NN + na) * TT + t) << 6);
            xb = xa + ((size_t)TT << 6);       // next n, same (b,t)
        } else {
            xa = in + ((size_t)(g * NN + na) << 6);
            xb = xa + 64;
        }
        float a0 = 0.f, a1 = 0.f, b0 = 0.f, b1 = 0.f;
        GAT_STEP(0, a0, b0)  GAT_STEP(1, a1, b1)
        GAT_STEP(2, a0, b0)  GAT_STEP(3, a1, b1)
        GAT_STEP(4, a0, b0)  GAT_STEP(5, a1, b1)
        GAT_STEP(6, a0, b0)  GAT_STEP(7, a1, b1)
        GAT_STEP(8, a0, b0)  GAT_STEP(9, a1, b1)
        GAT_STEP(10, a0, b0) GAT_STEP(11, a1, b1)
        GAT_STEP(12, a0, b0) GAT_STEP(13, a1, b1)
        GAT_STEP(14, a0, b0) GAT_STEP(15, a1, b1)
        float acca = a0 + a1, accb = b0 + b1;
        // transposed store: [node][chan=lane][head]
        hlin[((size_t)(g * NN + na) << 8) + (lane << 2) + head] = acca;
        hlin[((size_t)(g * NN + nb) << 8) + (lane << 2) + head] = accb;
        float s1a = acca * as, s2a = acca * ad;
        float s1b = accb * as, s2b = accb * ad;
#pragma unroll
        for (int off = 32; off; off >>= 1) {
            s1a += __shfl_xor(s1a, off, 64);
            s2a += __shfl_xor(s2a, off, 64);
            s1b += __shfl_xor(s1b, off, 64);
            s2b += __shfl_xor(s2b, off, 64);
        }
        if (lane == 0) {
            asrc[(size_t)(g * NN + na) * NHEADS + head] = s1a;
            adst[(size_t)(g * NN + na) * NHEADS + head] = s2a;
            asrc[(size_t)(g * NN + nb) * NHEADS + head] = s1b;
            adst[(size_t)(g * NN + nb) * NHEADS + head] = s2b;
        }
    }
}

// ---------------- GAT edge softmax + aggregation ----------------
// One wave per destination node; per-64-edge chunk: parallel weight computation
// into LDS, then serial broadcast-aggregate with coalesced dwordx4 h loads.
// No max-subtraction: |e| <= ~10 for this data, exp() safe in fp32.
__global__ __launch_bounds__(256) void gat_edge(
    const float* __restrict__ hlin, const float* __restrict__ asrc,
    const float* __restrict__ adst, const int* __restrict__ offs,
    const int* __restrict__ csr, const float* __restrict__ bias,
    float* __restrict__ out, int do_relu) {
    __shared__ float pbuf[4][64][4];   // [wave][edge-in-chunk][head]
    __shared__ int   sbuf[4][64];
    __shared__ int   degs[4];
    int tid = threadIdx.x;
    int lane = tid & 63, w = tid >> 6;
    // XCD swizzle: graph g -> XCD g%8 (consecutive blockIdx round-robins XCDs)
    int B = blockIdx.x;
    int x = B & 7, j = B >> 3;             // j in 0..999
    int graph = x + 8 * (j / 250);
    int node = graph * NN + ((j % 250) << 2) + w;
    int beg = offs[node], end = offs[node + 1];
    int deg = end - beg;
    if (lane == 0) degs[w] = deg;
    __syncthreads();
    int maxdeg = max(max(degs[0], degs[1]), max(degs[2], degs[3]));
    int nchunk = (maxdeg + 63) >> 6;

    float4 ad = *(const float4*)(adst + (size_t)node * 4);
    const float* asrc_g = asrc + (size_t)graph * NN * 4;
    const float* hg = hlin + ((size_t)graph * NN << 8);

    float4 acc = make_float4(0.f, 0.f, 0.f, 0.f);
    float4 ssum = make_float4(0.f, 0.f, 0.f, 0.f);
    for (int c = 0; c < nchunk; ++c) {
        int e0 = beg + (c << 6);
        int myedge = e0 + lane;
        float4 p = make_float4(0.f, 0.f, 0.f, 0.f);
        int src = 0;
        if (myedge < end) {
            src = csr[myedge];
            float4 a = *(const float4*)(asrc_g + (size_t)src * 4);
            p.x = __expf(leaky_(a.x + ad.x));
            p.y = __expf(leaky_(a.y + ad.y));
            p.z = __expf(leaky_(a.z + ad.z));
            p.w = __expf(leaky_(a.w + ad.w));
        }
        // butterfly sum of this chunk's weights
        float4 t = p;
#pragma unroll
        for (int off = 1; off < 64; off <<= 1) {
            t.x += __shfl_xor(t.x, off, 64);
            t.y += __shfl_xor(t.y, off, 64);
            t.z += __shfl_xor(t.z, off, 64);
            t.w += __shfl_xor(t.w, off, 64);
        }
        ssum.x += t.x; ssum.y += t.y; ssum.z += t.z; ssum.w += t.w;
        *(float4*)&pbuf[w][lane][0] = p;
        sbuf[w][lane] = src;
        __syncthreads();
        int cnt = end - e0; if (cnt > 64) cnt = 64;
        for (int e = 0; e < cnt; ++e) {
            float4 pe = *(const float4*)&pbuf[w][e][0];   // broadcast
            int se = sbuf[w][e];                           // broadcast
            float4 hv = *(const float4*)(hg + (((size_t)se) << 8) + (lane << 2));
            acc.x = fmaf(pe.x, hv.x, acc.x);
            acc.y = fmaf(pe.y, hv.y, acc.y);
            acc.z = fmaf(pe.z, hv.z, acc.z);
            acc.w = fmaf(pe.w, hv.w, acc.w);
        }
        __syncthreads();
    }
    float o = 0.25f * (acc.x / ssum.x + acc.y / ssum.y + acc.z / ssum.z + acc.w / ssum.w)
            + bias[lane];
    if (do_relu) o = fmaxf(o, 0.f);
    out[((size_t)node << 6) + lane] = o;
}

// ---------------- GRU input-side GEMM: giseq[t][r][192] = bih + x_t[r] @ Wih^T ----------------
// v2: 3200 blocks (occupancy), 2-row ILP pairs, float4 x loads.
// MODE 0: input gat2out [G][N][64] gathered (g=b*T+t, row=(b,n)).  MODE 1: input [T][4000][64] flat.
template <int MODE>
__global__ __launch_bounds__(192) void gru_gi(
    const float* __restrict__ in, const float* __restrict__ Wih,
    const float* __restrict__ bih, float* __restrict__ giseq) {
    const int ROWS = 10;  // 3200 blocks * 10 = 32000 (t,row) pairs
    int j = threadIdx.x;  // 0..191
    float wrow[64];
#pragma unroll
    for (int f4 = 0; f4 < 16; ++f4) {
        float4 w = *(const float4*)(Wih + (size_t)j * 64 + f4 * 4);
        wrow[4 * f4 + 0] = w.x; wrow[4 * f4 + 1] = w.y;
        wrow[4 * f4 + 2] = w.z; wrow[4 * f4 + 3] = w.w;
    }
    float bj = bih[j];
    int q0 = blockIdx.x * ROWS;
    int t = q0 / NROWS;            // constant per block (NROWS % ROWS == 0)
    int r0 = q0 - t * NROWS;
    for (int rr = 0; rr < ROWS; rr += 2) {
        const float *xa, *xb;
        if (MODE == 0) {
            int ra = r0 + rr, rb = ra + 1;
            int ba = ra / NN, na = ra - ba * NN;
            int bb2 = rb / NN, nb = rb - bb2 * NN;
            xa = in + (((size_t)(ba * TT + t) * NN + na) << 6);
            xb = in + (((size_t)(bb2 * TT + t) * NN + nb) << 6);
        } else {
            xa = in + ((size_t)(q0 + rr) << 6);
            xb = xa + 64;
        }
        float acca = bj, accb = bj;
#pragma unroll
        for (int f4 = 0; f4 < 16; ++f4) {
            float4 a4 = *(const float4*)(xa + f4 * 4);
            float4 b4 = *(const float4*)(xb + f4 * 4);
            acca = fmaf(a4.x, wrow[4 * f4 + 0], acca);
            acca = fmaf(a4.y, wrow[4 * f4 + 1], acca);
            acca = fmaf(a4.z, wrow[4 * f4 + 2], acca);
            acca = fmaf(a4.w, wrow[4 * f4 + 3], acca);
            accb = fmaf(b4.x, wrow[4 * f4 + 0], accb);
            accb = fmaf(b4.y, wrow[4 * f4 + 1], accb);
            accb = fmaf(b4.z, wrow[4 * f4 + 2], accb);
            accb = fmaf(b4.w, wrow[4 * f4 + 3], accb);
        }
        giseq[(size_t)(q0 + rr) * 192 + j] = acca;
        giseq[(size_t)(q0 + rr + 1) * 192 + j] = accb;
    }
}

// ---------------- GRU recurrence v2 (Whh side only; gi precomputed) ----------------
// Thread ch owns the full gate triplet: Whh rows {ch, 64+ch, 128+ch} in 192 VGPRs.
// h-state in LDS, wave-private (wave w owns rows w*4..w*4+3) -> ZERO barriers.
// h reads are wave-uniform ds_read_b128 broadcasts (16 per row).
// LAYER 0: outseq = h1seq [T][4000][64] (store every t). LAYER 1: outseq = hT [4000][64].
template <int LAYER>
__global__ __launch_bounds__(128) void gru_rec(
    const float* __restrict__ giseq, const float* __restrict__ Whh,
    const float* __restrict__ bhh, float* __restrict__ outseq) {
    __shared__ float hs[8][64];       // 2 waves * 4 rows, wave-private regions
    int tid = threadIdx.x;
    int ch = tid & 63, w = tid >> 6;  // w in {0,1}
    float wr[64], wz[64], wn[64];
#pragma unroll
    for (int k4 = 0; k4 < 16; ++k4) {
        float4 a = *(const float4*)(Whh + (size_t)ch * 64 + k4 * 4);
        float4 b = *(const float4*)(Whh + (size_t)(64 + ch) * 64 + k4 * 4);
        float4 c = *(const float4*)(Whh + (size_t)(128 + ch) * 64 + k4 * 4);
        wr[4*k4+0] = a.x; wr[4*k4+1] = a.y; wr[4*k4+2] = a.z; wr[4*k4+3] = a.w;
        wz[4*k4+0] = b.x; wz[4*k4+1] = b.y; wz[4*k4+2] = b.z; wz[4*k4+3] = b.w;
        wn[4*k4+0] = c.x; wn[4*k4+1] = c.y; wn[4*k4+2] = c.z; wn[4*k4+3] = c.w;
    }
    float br = bhh[ch], bz = bhh[64 + ch], bn = bhh[128 + ch];
    int row0 = blockIdx.x * 8 + w * 4;
    float hprev[4];
#pragma unroll
    for (int r = 0; r < 4; ++r) { hs[w * 4 + r][ch] = 0.f; hprev[r] = 0.f; }

    for (int t = 0; t < TT; ++t) {
#pragma unroll
        for (int r = 0; r < 4; ++r) {
            int row = row0 + r;
            const float* gp = giseq + ((size_t)(t * NROWS + row)) * 192;
            float gir = gp[ch], giz = gp[64 + ch], gin = gp[128 + ch];
            float ar = br, az = bz, an = bn;
#pragma unroll
            for (int k4 = 0; k4 < 16; ++k4) {
                float4 h4 = *(const float4*)&hs[w * 4 + r][k4 * 4];  // broadcast
                ar = fmaf(h4.x, wr[4*k4+0], ar); ar = fmaf(h4.y, wr[4*k4+1], ar);
                ar = fmaf(h4.z, wr[4*k4+2], ar); ar = fmaf(h4.w, wr[4*k4+3], ar);
                az = fmaf(h4.x, wz[4*k4+0], az); az = fmaf(h4.y, wz[4*k4+1], az);
                az = fmaf(h4.z, wz[4*k4+2], az); az = fmaf(h4.w, wz[4*k4+3], az);
                an = fmaf(h4.x, wn[4*k4+0], an); an = fmaf(h4.y, wn[4*k4+1], an);
                an = fmaf(h4.z, wn[4*k4+2], an); an = fmaf(h4.w, wn[4*k4+3], an);
            }
            float rg = sigmoidf_(gir + ar);
            float zg = sigmoidf_(giz + az);
            float ng = tanhf_(gin + rg * an);
            float hnew = (1.f - zg) * ng + zg * hprev[r];
            hprev[r] = hnew;
            hs[w * 4 + r][ch] = hnew;   // same-wave LDS dep, compiler orders via lgkmcnt
            if (LAYER == 0)
                outseq[(((size_t)(t * NROWS + row)) << 6) + ch] = hnew;
        }
    }
    if (LAYER == 1) {
#pragma unroll
        for (int r = 0; r < 4; ++r)
            outseq[(((size_t)(row0 + r)) << 6) + ch] = hprev[r];
    }
}

// ---------------- final MLP ----------------
__global__ __launch_bounds__(64) void mlp_head(
    const float* __restrict__ hT, const float* __restrict__ pW1,
    const float* __restrict__ pb1, const float* __restrict__ pW2,
    const float* __restrict__ pb2, float* __restrict__ out) {
    int r = blockIdx.x, lane = threadIdx.x;
    __shared__ float hrow[64];
    __shared__ float mid[64];
    hrow[lane] = hT[((size_t)r << 6) + lane];
    __syncthreads();
    float acc = pb1[lane];
#pragma unroll
    for (int k = 0; k < 64; ++k) acc = fmaf(hrow[k], pW1[k * 64 + lane], acc);
    mid[lane] = fmaxf(acc, 0.f);
    __syncthreads();
    if (lane < 10) {
        float o = pb2[lane];
#pragma unroll
        for (int k = 0; k < 64; ++k) o = fmaf(mid[k], pW2[k * 10 + lane], o);
        out[(size_t)r * 10 + lane] = o;
    }
}

// ---------------- launch ----------------
extern "C" void kernel_launch(void* const* d_in, const int* in_sizes, int n_in,
                              void* d_out, int out_size, void* d_ws, size_t ws_size,
                              hipStream_t stream) {
    (void)in_sizes; (void)n_in; (void)out_size; (void)ws_size;
    const float* x    = (const float*)d_in[0];
    const int*   ei   = (const int*)d_in[1];
    const float* W1   = (const float*)d_in[3];
    const float* as1  = (const float*)d_in[4];
    const float* ad1  = (const float*)d_in[5];
    const float* b1   = (const float*)d_in[6];
    const float* W2   = (const float*)d_in[7];
    const float* as2  = (const float*)d_in[8];
    const float* ad2  = (const float*)d_in[9];
    const float* b2   = (const float*)d_in[10];
    const float* Wih0 = (const float*)d_in[13];
    const float* Whh0 = (const float*)d_in[14];
    const float* bih0 = (const float*)d_in[15];
    const float* bhh0 = (const float*)d_in[16];
    const float* Wih1 = (const float*)d_in[17];
    const float* Whh1 = (const float*)d_in[18];
    const float* bih1 = (const float*)d_in[19];
    const float* bhh1 = (const float*)d_in[20];
    const float* pW1  = (const float*)d_in[21];
    const float* pb1  = (const float*)d_in[22];
    const float* pW2  = (const float*)d_in[23];
    const float* pb2  = (const float*)d_in[24];
    float* out = (float*)d_out;

    // workspace layout (bytes); overlays noted
    char* ws = (char*)d_ws;
    float* hlin  = (float*)(ws + 0);           // 32,768,000  (overlay: giseq 24.58MB)
    float* giseq = hlin;
    float* asrc  = (float*)(ws + 32768000);    // 512,000     (overlay: hT 1MB spans asrc+adst)
    float* hT    = asrc;
    float* adst  = (float*)(ws + 33280000);    // 512,000
    float* gat1  = (float*)(ws + 33792000);    // 8,192,000   (overlay: h1seq)
    float* h1seq = gat1;
    float* gat2  = (float*)(ws + 41984000);    // 8,192,000
    int* counts  = (int*)(ws + 50176000);      // 128,000  (overlay: Wt1/Wt2 after scan)
    int* cursor  = (int*)(ws + 50304000);      // 128,000
    int* offs    = (int*)(ws + 50432000);      // 128,004 (padded to 128,256)
    int* csr     = (int*)(ws + 50560256);      // 2,176,000  -> total 52.7MB
    // Wt1/Wt2 overlay the counts+cursor region (dead after scatter_edges):
    float* Wt1 = (float*)(ws + 50176000);      // 65,536
    float* Wt2 = (float*)(ws + 50176000 + 65536);  // 65,536 (fits in 256,000)

    hipMemsetAsync(counts, 0, 2 * GN * sizeof(int), stream);  // counts + cursor (adjacent)

    dim3 egrid((E2 + 255) / 256, GG);
    count_edges<<<egrid, 256, 0, stream>>>(ei, counts);
    scan_offsets_pg<<<GG, 256, 0, stream>>>(counts, offs);
    scatter_edges<<<egrid, 256, 0, stream>>>(ei, offs, cursor, csr);
    transpose_w<<<64, 256, 0, stream>>>(W1, W2, Wt1, Wt2);   // counts/cursor now dead

    gat_linear<0><<<GG * 50, 256, 0, stream>>>(x, Wt1, as1, ad1, hlin, asrc, adst);
    gat_edge<<<GN / 4, 256, 0, stream>>>(hlin, asrc, adst, offs, csr, b1, gat1, 1);
    gat_linear<1><<<GG * 50, 256, 0, stream>>>(gat1, Wt2, as2, ad2, hlin, asrc, adst);
    gat_edge<<<GN / 4, 256, 0, stream>>>(hlin, asrc, adst, offs, csr, b2, gat2, 0);

    gru_gi<0><<<3200, 192, 0, stream>>>(gat2, Wih0, bih0, giseq);
    gru_rec<0><<<500, 128, 0, stream>>>(giseq, Whh0, bhh0, h1seq);
    gru_gi<1><<<3200, 192, 0, stream>>>(h1seq, Wih1, bih1, giseq);
    gru_rec<1><<<500, 128, 0, stream>>>(giseq, Whh1, bhh1, hT);

    mlp_head<<<NROWS, 64, 0, stream>>>(hT, pW1, pb1, pW2, pb2, out);
}

// Round 7
// 505.372 us; speedup vs baseline: 1.0193x; 1.0193x over previous
//
#include <hip/hip_runtime.h>
#include <math.h>

// Problem constants
#define BB 4
#define NN 1000
#define TT 8
#define FF 64
#define HH 64
#define NHEADS 4
#define EE 16000
#define E2 17000          // EE + NN self-loops (EXACT per-graph edge total)
#define GG (BB*TT)        // 32 graphs
#define GN (GG*NN)        // 32000 (graph,node) pairs
#define NROWS (BB*NN)     // 4000 GRU rows

// ---------------- helpers ----------------
__device__ __forceinline__ float sigmoidf_(float x) {
    return 1.f / (1.f + __expf(-x));
}
__device__ __forceinline__ float tanhf_(float x) {
    x = fminf(fmaxf(x, -15.f), 15.f);
    float e = __expf(2.f * x);
    return (e - 1.f) / (e + 1.f);
}
__device__ __forceinline__ float leaky_(float x) {
    return (x > 0.f) ? x : 0.2f * x;
}

// ---------------- CSR build ----------------
__global__ void count_edges(const int* __restrict__ ei, int* __restrict__ counts) {
    int g = blockIdx.y;
    int e = blockIdx.x * 256 + threadIdx.x;
    if (e >= E2) return;
    int dst;
    if (e < EE) dst = ei[(size_t)g * 2 * EE + EE + e];
    else        dst = e - EE;   // self-loop
    atomicAdd(&counts[g * NN + dst], 1);
}

// Per-graph scan: each graph owns csr region [g*E2, (g+1)*E2); only a
// 1000-element scan per graph is needed. One 256-thread block per graph.
__global__ __launch_bounds__(256) void scan_offsets_pg(const int* __restrict__ counts,
                                                       int* __restrict__ offs) {
    __shared__ int tot[256];
    int g = blockIdx.x;
    int tid = threadIdx.x;
    int base = tid * 4;
    int c0 = 0, c1 = 0, c2 = 0, c3 = 0;
    if (base < NN) {
        int4 v = *(const int4*)(counts + (size_t)g * NN + base);  // 16B aligned (NN%4==0)
        c0 = v.x; c1 = v.y; c2 = v.z; c3 = v.w;
    }
    int s = c0 + c1 + c2 + c3;
    tot[tid] = s;
    __syncthreads();
    // Hillis-Steele inclusive scan over 256 partials
    for (int off = 1; off < 256; off <<= 1) {
        int y = (tid >= off) ? tot[tid - off] : 0;
        __syncthreads();
        tot[tid] += y;
        __syncthreads();
    }
    int run = g * E2 + tot[tid] - s;  // exclusive prefix + graph base
    if (base < NN) {
        int4 o;
        o.x = run; run += c0;
        o.y = run; run += c1;
        o.z = run; run += c2;
        o.w = run;
        *(int4*)(offs + (size_t)g * NN + base) = o;
    }
    if (g == 0 && tid == 0) offs[GN] = GG * E2;
}

__global__ void scatter_edges(const int* __restrict__ ei, const int* __restrict__ offs,
                              int* __restrict__ cursor, int* __restrict__ csr) {
    int g = blockIdx.y;
    int e = blockIdx.x * 256 + threadIdx.x;
    if (e >= E2) return;
    int src, dst;
    if (e < EE) {
        src = ei[(size_t)g * 2 * EE + e];
        dst = ei[(size_t)g * 2 * EE + EE + e];
    } else {
        src = dst = e - EE;
    }
    int i = g * NN + dst;
    int pos = offs[i] + atomicAdd(&cursor[i], 1);
    csr[pos] = src;
}

// ---------------- W transpose prep: Wt[col][f] = W[f][col] ----------------
__global__ void transpose_w(const float* __restrict__ W1, const float* __restrict__ W2,
                            float* __restrict__ Wt1, float* __restrict__ Wt2) {
    int f = blockIdx.x;      // 0..63
    int c = threadIdx.x;     // 0..255
    Wt1[(size_t)c * 64 + f] = W1[(size_t)f * 256 + c];
    Wt2[(size_t)c * 64 + f] = W2[(size_t)f * 256 + c];
}

// Register pin: value becomes an asm-defined VGPR the compiler CANNOT
// rematerialize from memory (R5/R6: regalloc kept re-loading W, VGPR stuck
// at 44 and the kernel was L2-BW-bound on ~1 GB/dispatch of W refetch).
#define PIN64_(arr)                                        \
    _Pragma("unroll")                                      \
    for (int _pi = 0; _pi < 64; ++_pi)                     \
        asm volatile("" : "+v"((arr)[_pi]));

// ---------------- GAT linear v5 ----------------
// W register-resident via asm pin. ROWS=20 (1600 blocks). Dual accumulator
// chains per row. x-row loads are wave-uniform float4 broadcasts.
template <int MODE>
__global__ __launch_bounds__(256, 4) void gat_linear(
    const float* __restrict__ in, const float* __restrict__ Wt,
    const float* __restrict__ att_s, const float* __restrict__ att_d,
    float* __restrict__ hlin, float* __restrict__ asrc, float* __restrict__ adst) {
    const int ROWS = 20;
    const int CH = NN / ROWS;  // 50 -> 1600 blocks
    int g = blockIdx.x / CH;
    int n0 = (blockIdx.x % CH) * ROWS;
    int tid = threadIdx.x;
    float w[FF];
#pragma unroll
    for (int i = 0; i < 16; ++i) {
        float4 v = *(const float4*)(Wt + (size_t)tid * 64 + i * 4);
        w[4 * i + 0] = v.x; w[4 * i + 1] = v.y;
        w[4 * i + 2] = v.z; w[4 * i + 3] = v.w;
    }
    PIN64_(w)
    int head = tid >> 6, lane = tid & 63;
    float as = att_s[head * HH + lane];
    float ad = att_d[head * HH + lane];
    int b = g / TT, t = g % TT;
    for (int rr = 0; rr < ROWS; rr += 2) {
        int na = n0 + rr, nb = na + 1;
        const float *xa, *xb;
        if (MODE == 0) {
            xa = in + (((size_t)(b * NN + na) * TT + t) << 6);
            xb = xa + ((size_t)TT << 6);       // next n, same (b,t)
        } else {
            xa = in + ((size_t)(g * NN + na) << 6);
            xb = xa + 64;
        }
        float a0 = 0.f, a1 = 0.f, b0 = 0.f, b1 = 0.f;
#pragma unroll
        for (int i = 0; i < 16; ++i) {
            float4 a4 = ((const float4*)xa)[i];
            float4 b4 = ((const float4*)xb)[i];
            float& accA = (i & 1) ? a1 : a0;
            float& accB = (i & 1) ? b1 : b0;
            accA = fmaf(a4.x, w[4 * i + 0], accA);
            accA = fmaf(a4.y, w[4 * i + 1], accA);
            accA = fmaf(a4.z, w[4 * i + 2], accA);
            accA = fmaf(a4.w, w[4 * i + 3], accA);
            accB = fmaf(b4.x, w[4 * i + 0], accB);
            accB = fmaf(b4.y, w[4 * i + 1], accB);
            accB = fmaf(b4.z, w[4 * i + 2], accB);
            accB = fmaf(b4.w, w[4 * i + 3], accB);
        }
        float acca = a0 + a1, accb = b0 + b1;
        // transposed store: [node][chan=lane][head]
        hlin[((size_t)(g * NN + na) << 8) + (lane << 2) + head] = acca;
        hlin[((size_t)(g * NN + nb) << 8) + (lane << 2) + head] = accb;
        float s1a = acca * as, s2a = acca * ad;
        float s1b = accb * as, s2b = accb * ad;
#pragma unroll
        for (int off = 32; off; off >>= 1) {
            s1a += __shfl_xor(s1a, off, 64);
            s2a += __shfl_xor(s2a, off, 64);
            s1b += __shfl_xor(s1b, off, 64);
            s2b += __shfl_xor(s2b, off, 64);
        }
        if (lane == 0) {
            asrc[(size_t)(g * NN + na) * NHEADS + head] = s1a;
            adst[(size_t)(g * NN + na) * NHEADS + head] = s2a;
            asrc[(size_t)(g * NN + nb) * NHEADS + head] = s1b;
            adst[(size_t)(g * NN + nb) * NHEADS + head] = s2b;
        }
    }
}

// ---------------- GAT edge softmax + aggregation ----------------
// One wave per destination node; per-64-edge chunk: parallel weight computation
// into LDS, then serial broadcast-aggregate with coalesced dwordx4 h loads.
// No max-subtraction: |e| <= ~10 for this data, exp() safe in fp32.
__global__ __launch_bounds__(256) void gat_edge(
    const float* __restrict__ hlin, const float* __restrict__ asrc,
    const float* __restrict__ adst, const int* __restrict__ offs,
    const int* __restrict__ csr, const float* __restrict__ bias,
    float* __restrict__ out, int do_relu) {
    __shared__ float pbuf[4][64][4];   // [wave][edge-in-chunk][head]
    __shared__ int   sbuf[4][64];
    __shared__ int   degs[4];
    int tid = threadIdx.x;
    int lane = tid & 63, w = tid >> 6;
    // XCD swizzle: graph g -> XCD g%8 (consecutive blockIdx round-robins XCDs)
    int B = blockIdx.x;
    int x = B & 7, j = B >> 3;             // j in 0..999
    int graph = x + 8 * (j / 250);
    int node = graph * NN + ((j % 250) << 2) + w;
    int beg = offs[node], end = offs[node + 1];
    int deg = end - beg;
    if (lane == 0) degs[w] = deg;
    __syncthreads();
    int maxdeg = max(max(degs[0], degs[1]), max(degs[2], degs[3]));
    int nchunk = (maxdeg + 63) >> 6;

    float4 ad = *(const float4*)(adst + (size_t)node * 4);
    const float* asrc_g = asrc + (size_t)graph * NN * 4;
    const float* hg = hlin + ((size_t)graph * NN << 8);

    float4 acc = make_float4(0.f, 0.f, 0.f, 0.f);
    float4 ssum = make_float4(0.f, 0.f, 0.f, 0.f);
    for (int c = 0; c < nchunk; ++c) {
        int e0 = beg + (c << 6);
        int myedge = e0 + lane;
        float4 p = make_float4(0.f, 0.f, 0.f, 0.f);
        int src = 0;
        if (myedge < end) {
            src = csr[myedge];
            float4 a = *(const float4*)(asrc_g + (size_t)src * 4);
            p.x = __expf(leaky_(a.x + ad.x));
            p.y = __expf(leaky_(a.y + ad.y));
            p.z = __expf(leaky_(a.z + ad.z));
            p.w = __expf(leaky_(a.w + ad.w));
        }
        // butterfly sum of this chunk's weights
        float4 t = p;
#pragma unroll
        for (int off = 1; off < 64; off <<= 1) {
            t.x += __shfl_xor(t.x, off, 64);
            t.y += __shfl_xor(t.y, off, 64);
            t.z += __shfl_xor(t.z, off, 64);
            t.w += __shfl_xor(t.w, off, 64);
        }
        ssum.x += t.x; ssum.y += t.y; ssum.z += t.z; ssum.w += t.w;
        *(float4*)&pbuf[w][lane][0] = p;
        sbuf[w][lane] = src;
        __syncthreads();
        int cnt = end - e0; if (cnt > 64) cnt = 64;
        for (int e = 0; e < cnt; ++e) {
            float4 pe = *(const float4*)&pbuf[w][e][0];   // broadcast
            int se = sbuf[w][e];                           // broadcast
            float4 hv = *(const float4*)(hg + (((size_t)se) << 8) + (lane << 2));
            acc.x = fmaf(pe.x, hv.x, acc.x);
            acc.y = fmaf(pe.y, hv.y, acc.y);
            acc.z = fmaf(pe.z, hv.z, acc.z);
            acc.w = fmaf(pe.w, hv.w, acc.w);
        }
        __syncthreads();
    }
    float o = 0.25f * (acc.x / ssum.x + acc.y / ssum.y + acc.z / ssum.z + acc.w / ssum.w)
            + bias[lane];
    if (do_relu) o = fmaxf(o, 0.f);
    out[((size_t)node << 6) + lane] = o;
}

// ---------------- GRU input-side GEMM: giseq[t][r][192] = bih + x_t[r] @ Wih^T ----------------
// v3: W pinned register-resident (asm), launch_bounds(192,4), 3200 blocks,
// 2-row ILP pairs, float4 x loads.
// MODE 0: input gat2out [G][N][64] gathered (g=b*T+t, row=(b,n)).  MODE 1: input [T][4000][64] flat.
template <int MODE>
__global__ __launch_bounds__(192, 4) void gru_gi(
    const float* __restrict__ in, const float* __restrict__ Wih,
    const float* __restrict__ bih, float* __restrict__ giseq) {
    const int ROWS = 10;  // 3200 blocks * 10 = 32000 (t,row) pairs
    int j = threadIdx.x;  // 0..191
    float wrow[64];
#pragma unroll
    for (int f4 = 0; f4 < 16; ++f4) {
        float4 w = *(const float4*)(Wih + (size_t)j * 64 + f4 * 4);
        wrow[4 * f4 + 0] = w.x; wrow[4 * f4 + 1] = w.y;
        wrow[4 * f4 + 2] = w.z; wrow[4 * f4 + 3] = w.w;
    }
    PIN64_(wrow)
    float bj = bih[j];
    int q0 = blockIdx.x * ROWS;
    int t = q0 / NROWS;            // constant per block (NROWS % ROWS == 0)
    int r0 = q0 - t * NROWS;
    for (int rr = 0; rr < ROWS; rr += 2) {
        const float *xa, *xb;
        if (MODE == 0) {
            int ra = r0 + rr, rb = ra + 1;
            int ba = ra / NN, na = ra - ba * NN;
            int bb2 = rb / NN, nb = rb - bb2 * NN;
            xa = in + (((size_t)(ba * TT + t) * NN + na) << 6);
            xb = in + (((size_t)(bb2 * TT + t) * NN + nb) << 6);
        } else {
            xa = in + ((size_t)(q0 + rr) << 6);
            xb = xa + 64;
        }
        float acca = bj, accb = bj;
#pragma unroll
        for (int f4 = 0; f4 < 16; ++f4) {
            float4 a4 = *(const float4*)(xa + f4 * 4);
            float4 b4 = *(const float4*)(xb + f4 * 4);
            acca = fmaf(a4.x, wrow[4 * f4 + 0], acca);
            acca = fmaf(a4.y, wrow[4 * f4 + 1], acca);
            acca = fmaf(a4.z, wrow[4 * f4 + 2], acca);
            acca = fmaf(a4.w, wrow[4 * f4 + 3], acca);
            accb = fmaf(b4.x, wrow[4 * f4 + 0], accb);
            accb = fmaf(b4.y, wrow[4 * f4 + 1], accb);
            accb = fmaf(b4.z, wrow[4 * f4 + 2], accb);
            accb = fmaf(b4.w, wrow[4 * f4 + 3], accb);
        }
        giseq[(size_t)(q0 + rr) * 192 + j] = acca;
        giseq[(size_t)(q0 + rr + 1) * 192 + j] = accb;
    }
}

// ---------------- GRU recurrence v2 (Whh side only; gi precomputed) ----------------
// Thread ch owns the full gate triplet: Whh rows {ch, 64+ch, 128+ch} in 192 VGPRs.
// h-state in LDS, wave-private (wave w owns rows w*4..w*4+3) -> ZERO barriers.
// h reads are wave-uniform ds_read_b128 broadcasts (16 per row).
// LAYER 0: outseq = h1seq [T][4000][64] (store every t). LAYER 1: outseq = hT [4000][64].
template <int LAYER>
__global__ __launch_bounds__(128) void gru_rec(
    const float* __restrict__ giseq, const float* __restrict__ Whh,
    const float* __restrict__ bhh, float* __restrict__ outseq) {
    __shared__ float hs[8][64];       // 2 waves * 4 rows, wave-private regions
    int tid = threadIdx.x;
    int ch = tid & 63, w = tid >> 6;  // w in {0,1}
    float wr[64], wz[64], wn[64];
#pragma unroll
    for (int k4 = 0; k4 < 16; ++k4) {
        float4 a = *(const float4*)(Whh + (size_t)ch * 64 + k4 * 4);
        float4 b = *(const float4*)(Whh + (size_t)(64 + ch) * 64 + k4 * 4);
        float4 c = *(const float4*)(Whh + (size_t)(128 + ch) * 64 + k4 * 4);
        wr[4*k4+0] = a.x; wr[4*k4+1] = a.y; wr[4*k4+2] = a.z; wr[4*k4+3] = a.w;
        wz[4*k4+0] = b.x; wz[4*k4+1] = b.y; wz[4*k4+2] = b.z; wz[4*k4+3] = b.w;
        wn[4*k4+0] = c.x; wn[4*k4+1] = c.y; wn[4*k4+2] = c.z; wn[4*k4+3] = c.w;
    }
    float br = bhh[ch], bz = bhh[64 + ch], bn = bhh[128 + ch];
    int row0 = blockIdx.x * 8 + w * 4;
    float hprev[4];
#pragma unroll
    for (int r = 0; r < 4; ++r) { hs[w * 4 + r][ch] = 0.f; hprev[r] = 0.f; }

    for (int t = 0; t < TT; ++t) {
#pragma unroll
        for (int r = 0; r < 4; ++r) {
            int row = row0 + r;
            const float* gp = giseq + ((size_t)(t * NROWS + row)) * 192;
            float gir = gp[ch], giz = gp[64 + ch], gin = gp[128 + ch];
            float ar = br, az = bz, an = bn;
#pragma unroll
            for (int k4 = 0; k4 < 16; ++k4) {
                float4 h4 = *(const float4*)&hs[w * 4 + r][k4 * 4];  // broadcast
                ar = fmaf(h4.x, wr[4*k4+0], ar); ar = fmaf(h4.y, wr[4*k4+1], ar);
                ar = fmaf(h4.z, wr[4*k4+2], ar); ar = fmaf(h4.w, wr[4*k4+3], ar);
                az = fmaf(h4.x, wz[4*k4+0], az); az = fmaf(h4.y, wz[4*k4+1], az);
                az = fmaf(h4.z, wz[4*k4+2], az); az = fmaf(h4.w, wz[4*k4+3], az);
                an = fmaf(h4.x, wn[4*k4+0], an); an = fmaf(h4.y, wn[4*k4+1], an);
                an = fmaf(h4.z, wn[4*k4+2], an); an = fmaf(h4.w, wn[4*k4+3], an);
            }
            float rg = sigmoidf_(gir + ar);
            float zg = sigmoidf_(giz + az);
            float ng = tanhf_(gin + rg * an);
            float hnew = (1.f - zg) * ng + zg * hprev[r];
            hprev[r] = hnew;
            hs[w * 4 + r][ch] = hnew;   // same-wave LDS dep, compiler orders via lgkmcnt
            if (LAYER == 0)
                outseq[(((size_t)(t * NROWS + row)) << 6) + ch] = hnew;
        }
    }
    if (LAYER == 1) {
#pragma unroll
        for (int r = 0; r < 4; ++r)
            outseq[(((size_t)(row0 + r)) << 6) + ch] = hprev[r];
    }
}

// ---------------- final MLP ----------------
__global__ __launch_bounds__(64) void mlp_head(
    const float* __restrict__ hT, const float* __restrict__ pW1,
    const float* __restrict__ pb1, const float* __restrict__ pW2,
    const float* __restrict__ pb2, float* __restrict__ out) {
    int r = blockIdx.x, lane = threadIdx.x;
    __shared__ float hrow[64];
    __shared__ float mid[64];
    hrow[lane] = hT[((size_t)r << 6) + lane];
    __syncthreads();
    float acc = pb1[lane];
#pragma unroll
    for (int k = 0; k < 64; ++k) acc = fmaf(hrow[k], pW1[k * 64 + lane], acc);
    mid[lane] = fmaxf(acc, 0.f);
    __syncthreads();
    if (lane < 10) {
        float o = pb2[lane];
#pragma unroll
        for (int k = 0; k < 64; ++k) o = fmaf(mid[k], pW2[k * 10 + lane], o);
        out[(size_t)r * 10 + lane] = o;
    }
}

// ---------------- launch ----------------
extern "C" void kernel_launch(void* const* d_in, const int* in_sizes, int n_in,
                              void* d_out, int out_size, void* d_ws, size_t ws_size,
                              hipStream_t stream) {
    (void)in_sizes; (void)n_in; (void)out_size; (void)ws_size;
    const float* x    = (const float*)d_in[0];
    const int*   ei   = (const int*)d_in[1];
    const float* W1   = (const float*)d_in[3];
    const float* as1  = (const float*)d_in[4];
    const float* ad1  = (const float*)d_in[5];
    const float* b1   = (const float*)d_in[6];
    const float* W2   = (const float*)d_in[7];
    const float* as2  = (const float*)d_in[8];
    const float* ad2  = (const float*)d_in[9];
    const float* b2   = (const float*)d_in[10];
    const float* Wih0 = (const float*)d_in[13];
    const float* Whh0 = (const float*)d_in[14];
    const float* bih0 = (const float*)d_in[15];
    const float* bhh0 = (const float*)d_in[16];
    const float* Wih1 = (const float*)d_in[17];
    const float* Whh1 = (const float*)d_in[18];
    const float* bih1 = (const float*)d_in[19];
    const float* bhh1 = (const float*)d_in[20];
    const float* pW1  = (const float*)d_in[21];
    const float* pb1  = (const float*)d_in[22];
    const float* pW2  = (const float*)d_in[23];
    const float* pb2  = (const float*)d_in[24];
    float* out = (float*)d_out;

    // workspace layout (bytes); overlays noted
    char* ws = (char*)d_ws;
    float* hlin  = (float*)(ws + 0);           // 32,768,000  (overlay: giseq 24.58MB)
    float* giseq = hlin;
    float* asrc  = (float*)(ws + 32768000);    // 512,000     (overlay: hT 1MB spans asrc+adst)
    float* hT    = asrc;
    float* adst  = (float*)(ws + 33280000);    // 512,000
    float* gat1  = (float*)(ws + 33792000);    // 8,192,000   (overlay: h1seq)
    float* h1seq = gat1;
    float* gat2  = (float*)(ws + 41984000);    // 8,192,000
    int* counts  = (int*)(ws + 50176000);      // 128,000  (overlay: Wt1/Wt2 after scan)
    int* cursor  = (int*)(ws + 50304000);      // 128,000
    int* offs    = (int*)(ws + 50432000);      // 128,004 (padded to 128,256)
    int* csr     = (int*)(ws + 50560256);      // 2,176,000  -> total 52.7MB
    // Wt1/Wt2 overlay the counts+cursor region (dead after scatter_edges):
    float* Wt1 = (float*)(ws + 50176000);      // 65,536
    float* Wt2 = (float*)(ws + 50176000 + 65536);  // 65,536 (fits in 256,000)

    hipMemsetAsync(counts, 0, 2 * GN * sizeof(int), stream);  // counts + cursor (adjacent)

    dim3 egrid((E2 + 255) / 256, GG);
    count_edges<<<egrid, 256, 0, stream>>>(ei, counts);
    scan_offsets_pg<<<GG, 256, 0, stream>>>(counts, offs);
    scatter_edges<<<egrid, 256, 0, stream>>>(ei, offs, cursor, csr);
    transpose_w<<<64, 256, 0, stream>>>(W1, W2, Wt1, Wt2);   // counts/cursor now dead

    gat_linear<0><<<GG * 50, 256, 0, stream>>>(x, Wt1, as1, ad1, hlin, asrc, adst);
    gat_edge<<<GN / 4, 256, 0, stream>>>(hlin, asrc, adst, offs, csr, b1, gat1, 1);
    gat_linear<1><<<GG * 50, 256, 0, stream>>>(gat1, Wt2, as2, ad2, hlin, asrc, adst);
    gat_edge<<<GN / 4, 256, 0, stream>>>(hlin, asrc, adst, offs, csr, b2, gat2, 0);

    gru_gi<0><<<3200, 192, 0, stream>>>(gat2, Wih0, bih0, giseq);
    gru_rec<0><<<500, 128, 0, stream>>>(giseq, Whh0, bhh0, h1seq);
    gru_gi<1><<<3200, 192, 0, stream>>>(h1seq, Wih1, bih1, giseq);
    gru_rec<1><<<500, 128, 0, stream>>>(giseq, Whh1, bhh1, hT);

    mlp_head<<<NROWS, 64, 0, stream>>>(hT, pW1, pb1, pW2, pb2, out);
}

// Round 8
// 435.335 us; speedup vs baseline: 1.1833x; 1.1609x over previous
//
#include <hip/hip_runtime.h>
#include <math.h>

// Problem constants
#define BB 4
#define NN 1000
#define TT 8
#define FF 64
#define HH 64
#define NHEADS 4
#define EE 16000
#define E2 17000          // EE + NN self-loops (EXACT per-graph edge total)
#define GG (BB*TT)        // 32 graphs
#define GN (GG*NN)        // 32000 (graph,node) pairs
#define NROWS (BB*NN)     // 4000 GRU rows

// ---------------- helpers ----------------
__device__ __forceinline__ float sigmoidf_(float x) {
    return 1.f / (1.f + __expf(-x));
}
__device__ __forceinline__ float tanhf_(float x) {
    x = fminf(fmaxf(x, -15.f), 15.f);
    float e = __expf(2.f * x);
    return (e - 1.f) / (e + 1.f);
}
__device__ __forceinline__ float leaky_(float x) {
    return (x > 0.f) ? x : 0.2f * x;
}

// ---------------- CSR build ----------------
__global__ void count_edges(const int* __restrict__ ei, int* __restrict__ counts) {
    int g = blockIdx.y;
    int e = blockIdx.x * 256 + threadIdx.x;
    if (e >= E2) return;
    int dst;
    if (e < EE) dst = ei[(size_t)g * 2 * EE + EE + e];
    else        dst = e - EE;   // self-loop
    atomicAdd(&counts[g * NN + dst], 1);
}

// Per-graph scan: each graph owns csr region [g*E2, (g+1)*E2); only a
// 1000-element scan per graph is needed. One 256-thread block per graph.
__global__ __launch_bounds__(256) void scan_offsets_pg(const int* __restrict__ counts,
                                                       int* __restrict__ offs) {
    __shared__ int tot[256];
    int g = blockIdx.x;
    int tid = threadIdx.x;
    int base = tid * 4;
    int c0 = 0, c1 = 0, c2 = 0, c3 = 0;
    if (base < NN) {
        int4 v = *(const int4*)(counts + (size_t)g * NN + base);  // 16B aligned (NN%4==0)
        c0 = v.x; c1 = v.y; c2 = v.z; c3 = v.w;
    }
    int s = c0 + c1 + c2 + c3;
    tot[tid] = s;
    __syncthreads();
    // Hillis-Steele inclusive scan over 256 partials
    for (int off = 1; off < 256; off <<= 1) {
        int y = (tid >= off) ? tot[tid - off] : 0;
        __syncthreads();
        tot[tid] += y;
        __syncthreads();
    }
    int run = g * E2 + tot[tid] - s;  // exclusive prefix + graph base
    if (base < NN) {
        int4 o;
        o.x = run; run += c0;
        o.y = run; run += c1;
        o.z = run; run += c2;
        o.w = run;
        *(int4*)(offs + (size_t)g * NN + base) = o;
    }
    if (g == 0 && tid == 0) offs[GN] = GG * E2;
}

__global__ void scatter_edges(const int* __restrict__ ei, const int* __restrict__ offs,
                              int* __restrict__ cursor, int* __restrict__ csr) {
    int g = blockIdx.y;
    int e = blockIdx.x * 256 + threadIdx.x;
    if (e >= E2) return;
    int src, dst;
    if (e < EE) {
        src = ei[(size_t)g * 2 * EE + e];
        dst = ei[(size_t)g * 2 * EE + EE + e];
    } else {
        src = dst = e - EE;
    }
    int i = g * NN + dst;
    int pos = offs[i] + atomicAdd(&cursor[i], 1);
    csr[pos] = src;
}

// Register pin (used by gru_gi; kept from R7 to avoid confounds there)
#define PIN64_(arr)                                        \
    _Pragma("unroll")                                      \
    for (int _pi = 0; _pi < 64; ++_pi)                     \
        asm volatile("" : "+v"((arr)[_pi]));

// ---------------- GAT linear (v2 revert + occupancy) ----------------
// EXACT R4-measured v2 body (47 us: wcol strided loads, wave-uniform scalar
// x loads -> s_load + v_fmac-with-SGPR). Single change: ROWS 40->10
// (800->3200 blocks) for wave-level latency hiding of the s_load chains.
// R5-R7 restructures (float4 x, launch_bounds(,4), asm pin) all regressed or
// were neutral — reverted.
// hlin layout: [node][chan][head] (head fastest, float4 per chan)
// MODE 0: input is x [B,N,T,F] gathered per graph g=(b,t).  MODE 1: input [G,N,F] contiguous.
template <int MODE>
__global__ __launch_bounds__(256) void gat_linear(
    const float* __restrict__ in, const float* __restrict__ W,
    const float* __restrict__ att_s, const float* __restrict__ att_d,
    float* __restrict__ hlin, float* __restrict__ asrc, float* __restrict__ adst) {
    const int ROWS = 10;
    const int CH = NN / ROWS;  // 100 -> 3200 blocks
    int g = blockIdx.x / CH;
    int n0 = (blockIdx.x % CH) * ROWS;
    int tid = threadIdx.x;
    // W column into registers: W[f][tid]
    float wcol[FF];
#pragma unroll
    for (int f = 0; f < FF; ++f) wcol[f] = W[f * 256 + tid];
    int head = tid >> 6, lane = tid & 63;
    float as = att_s[head * HH + lane];
    float ad = att_d[head * HH + lane];
    int b = g / TT, t = g % TT;
    for (int r = 0; r < ROWS; ++r) {
        int n = n0 + r;
        const float* xrow;
        if (MODE == 0) xrow = in + (((size_t)(b * NN + n) * TT + t) * FF);
        else           xrow = in + ((size_t)(g * NN + n) * FF);
        float acc = 0.f;
#pragma unroll
        for (int f = 0; f < FF; ++f) acc = fmaf(xrow[f], wcol[f], acc);
        // transposed store: [node][chan=lane][head]
        hlin[((size_t)(g * NN + n) << 8) + (lane << 2) + head] = acc;
        float s1 = acc * as, s2 = acc * ad;
#pragma unroll
        for (int off = 32; off; off >>= 1) {
            s1 += __shfl_xor(s1, off, 64);
            s2 += __shfl_xor(s2, off, 64);
        }
        if (lane == 0) {
            asrc[(size_t)(g * NN + n) * NHEADS + head] = s1;
            adst[(size_t)(g * NN + n) * NHEADS + head] = s2;
        }
    }
}

// ---------------- GAT edge softmax + aggregation ----------------
// One wave per destination node; per-64-edge chunk: parallel weight computation
// into LDS, then serial broadcast-aggregate with coalesced dwordx4 h loads.
// No max-subtraction: |e| <= ~10 for this data, exp() safe in fp32.
__global__ __launch_bounds__(256) void gat_edge(
    const float* __restrict__ hlin, const float* __restrict__ asrc,
    const float* __restrict__ adst, const int* __restrict__ offs,
    const int* __restrict__ csr, const float* __restrict__ bias,
    float* __restrict__ out, int do_relu) {
    __shared__ float pbuf[4][64][4];   // [wave][edge-in-chunk][head]
    __shared__ int   sbuf[4][64];
    __shared__ int   degs[4];
    int tid = threadIdx.x;
    int lane = tid & 63, w = tid >> 6;
    // XCD swizzle: graph g -> XCD g%8 (consecutive blockIdx round-robins XCDs)
    int B = blockIdx.x;
    int x = B & 7, j = B >> 3;             // j in 0..999
    int graph = x + 8 * (j / 250);
    int node = graph * NN + ((j % 250) << 2) + w;
    int beg = offs[node], end = offs[node + 1];
    int deg = end - beg;
    if (lane == 0) degs[w] = deg;
    __syncthreads();
    int maxdeg = max(max(degs[0], degs[1]), max(degs[2], degs[3]));
    int nchunk = (maxdeg + 63) >> 6;

    float4 ad = *(const float4*)(adst + (size_t)node * 4);
    const float* asrc_g = asrc + (size_t)graph * NN * 4;
    const float* hg = hlin + ((size_t)graph * NN << 8);

    float4 acc = make_float4(0.f, 0.f, 0.f, 0.f);
    float4 ssum = make_float4(0.f, 0.f, 0.f, 0.f);
    for (int c = 0; c < nchunk; ++c) {
        int e0 = beg + (c << 6);
        int myedge = e0 + lane;
        float4 p = make_float4(0.f, 0.f, 0.f, 0.f);
        int src = 0;
        if (myedge < end) {
            src = csr[myedge];
            float4 a = *(const float4*)(asrc_g + (size_t)src * 4);
            p.x = __expf(leaky_(a.x + ad.x));
            p.y = __expf(leaky_(a.y + ad.y));
            p.z = __expf(leaky_(a.z + ad.z));
            p.w = __expf(leaky_(a.w + ad.w));
        }
        // butterfly sum of this chunk's weights
        float4 t = p;
#pragma unroll
        for (int off = 1; off < 64; off <<= 1) {
            t.x += __shfl_xor(t.x, off, 64);
            t.y += __shfl_xor(t.y, off, 64);
            t.z += __shfl_xor(t.z, off, 64);
            t.w += __shfl_xor(t.w, off, 64);
        }
        ssum.x += t.x; ssum.y += t.y; ssum.z += t.z; ssum.w += t.w;
        *(float4*)&pbuf[w][lane][0] = p;
        sbuf[w][lane] = src;
        __syncthreads();
        int cnt = end - e0; if (cnt > 64) cnt = 64;
        for (int e = 0; e < cnt; ++e) {
            float4 pe = *(const float4*)&pbuf[w][e][0];   // broadcast
            int se = sbuf[w][e];                           // broadcast
            float4 hv = *(const float4*)(hg + (((size_t)se) << 8) + (lane << 2));
            acc.x = fmaf(pe.x, hv.x, acc.x);
            acc.y = fmaf(pe.y, hv.y, acc.y);
            acc.z = fmaf(pe.z, hv.z, acc.z);
            acc.w = fmaf(pe.w, hv.w, acc.w);
        }
        __syncthreads();
    }
    float o = 0.25f * (acc.x / ssum.x + acc.y / ssum.y + acc.z / ssum.z + acc.w / ssum.w)
            + bias[lane];
    if (do_relu) o = fmaxf(o, 0.f);
    out[((size_t)node << 6) + lane] = o;
}

// ---------------- GRU input-side GEMM: giseq[t][r][192] = bih + x_t[r] @ Wih^T ----------------
// v3: W pinned register-resident (asm), launch_bounds(192,4), 3200 blocks,
// 2-row ILP pairs, float4 x loads.
// MODE 0: input gat2out [G][N][64] gathered (g=b*T+t, row=(b,n)).  MODE 1: input [T][4000][64] flat.
template <int MODE>
__global__ __launch_bounds__(192, 4) void gru_gi(
    const float* __restrict__ in, const float* __restrict__ Wih,
    const float* __restrict__ bih, float* __restrict__ giseq) {
    const int ROWS = 10;  // 3200 blocks * 10 = 32000 (t,row) pairs
    int j = threadIdx.x;  // 0..191
    float wrow[64];
#pragma unroll
    for (int f4 = 0; f4 < 16; ++f4) {
        float4 w = *(const float4*)(Wih + (size_t)j * 64 + f4 * 4);
        wrow[4 * f4 + 0] = w.x; wrow[4 * f4 + 1] = w.y;
        wrow[4 * f4 + 2] = w.z; wrow[4 * f4 + 3] = w.w;
    }
    PIN64_(wrow)
    float bj = bih[j];
    int q0 = blockIdx.x * ROWS;
    int t = q0 / NROWS;            // constant per block (NROWS % ROWS == 0)
    int r0 = q0 - t * NROWS;
    for (int rr = 0; rr < ROWS; rr += 2) {
        const float *xa, *xb;
        if (MODE == 0) {
            int ra = r0 + rr, rb = ra + 1;
            int ba = ra / NN, na = ra - ba * NN;
            int bb2 = rb / NN, nb = rb - bb2 * NN;
            xa = in + (((size_t)(ba * TT + t) * NN + na) << 6);
            xb = in + (((size_t)(bb2 * TT + t) * NN + nb) << 6);
        } else {
            xa = in + ((size_t)(q0 + rr) << 6);
            xb = xa + 64;
        }
        float acca = bj, accb = bj;
#pragma unroll
        for (int f4 = 0; f4 < 16; ++f4) {
            float4 a4 = *(const float4*)(xa + f4 * 4);
            float4 b4 = *(const float4*)(xb + f4 * 4);
            acca = fmaf(a4.x, wrow[4 * f4 + 0], acca);
            acca = fmaf(a4.y, wrow[4 * f4 + 1], acca);
            acca = fmaf(a4.z, wrow[4 * f4 + 2], acca);
            acca = fmaf(a4.w, wrow[4 * f4 + 3], acca);
            accb = fmaf(b4.x, wrow[4 * f4 + 0], accb);
            accb = fmaf(b4.y, wrow[4 * f4 + 1], accb);
            accb = fmaf(b4.z, wrow[4 * f4 + 2], accb);
            accb = fmaf(b4.w, wrow[4 * f4 + 3], accb);
        }
        giseq[(size_t)(q0 + rr) * 192 + j] = acca;
        giseq[(size_t)(q0 + rr + 1) * 192 + j] = accb;
    }
}

// ---------------- GRU recurrence v2 (Whh side only; gi precomputed) ----------------
// Thread ch owns the full gate triplet: Whh rows {ch, 64+ch, 128+ch} in 192 VGPRs.
// h-state in LDS, wave-private (wave w owns rows w*4..w*4+3) -> ZERO barriers.
// h reads are wave-uniform ds_read_b128 broadcasts (16 per row).
// LAYER 0: outseq = h1seq [T][4000][64] (store every t). LAYER 1: outseq = hT [4000][64].
template <int LAYER>
__global__ __launch_bounds__(128) void gru_rec(
    const float* __restrict__ giseq, const float* __restrict__ Whh,
    const float* __restrict__ bhh, float* __restrict__ outseq) {
    __shared__ float hs[8][64];       // 2 waves * 4 rows, wave-private regions
    int tid = threadIdx.x;
    int ch = tid & 63, w = tid >> 6;  // w in {0,1}
    float wr[64], wz[64], wn[64];
#pragma unroll
    for (int k4 = 0; k4 < 16; ++k4) {
        float4 a = *(const float4*)(Whh + (size_t)ch * 64 + k4 * 4);
        float4 b = *(const float4*)(Whh + (size_t)(64 + ch) * 64 + k4 * 4);
        float4 c = *(const float4*)(Whh + (size_t)(128 + ch) * 64 + k4 * 4);
        wr[4*k4+0] = a.x; wr[4*k4+1] = a.y; wr[4*k4+2] = a.z; wr[4*k4+3] = a.w;
        wz[4*k4+0] = b.x; wz[4*k4+1] = b.y; wz[4*k4+2] = b.z; wz[4*k4+3] = b.w;
        wn[4*k4+0] = c.x; wn[4*k4+1] = c.y; wn[4*k4+2] = c.z; wn[4*k4+3] = c.w;
    }
    float br = bhh[ch], bz = bhh[64 + ch], bn = bhh[128 + ch];
    int row0 = blockIdx.x * 8 + w * 4;
    float hprev[4];
#pragma unroll
    for (int r = 0; r < 4; ++r) { hs[w * 4 + r][ch] = 0.f; hprev[r] = 0.f; }

    for (int t = 0; t < TT; ++t) {
#pragma unroll
        for (int r = 0; r < 4; ++r) {
            int row = row0 + r;
            const float* gp = giseq + ((size_t)(t * NROWS + row)) * 192;
            float gir = gp[ch], giz = gp[64 + ch], gin = gp[128 + ch];
            float ar = br, az = bz, an = bn;
#pragma unroll
            for (int k4 = 0; k4 < 16; ++k4) {
                float4 h4 = *(const float4*)&hs[w * 4 + r][k4 * 4];  // broadcast
                ar = fmaf(h4.x, wr[4*k4+0], ar); ar = fmaf(h4.y, wr[4*k4+1], ar);
                ar = fmaf(h4.z, wr[4*k4+2], ar); ar = fmaf(h4.w, wr[4*k4+3], ar);
                az = fmaf(h4.x, wz[4*k4+0], az); az = fmaf(h4.y, wz[4*k4+1], az);
                az = fmaf(h4.z, wz[4*k4+2], az); az = fmaf(h4.w, wz[4*k4+3], az);
                an = fmaf(h4.x, wn[4*k4+0], an); an = fmaf(h4.y, wn[4*k4+1], an);
                an = fmaf(h4.z, wn[4*k4+2], an); an = fmaf(h4.w, wn[4*k4+3], an);
            }
            float rg = sigmoidf_(gir + ar);
            float zg = sigmoidf_(giz + az);
            float ng = tanhf_(gin + rg * an);
            float hnew = (1.f - zg) * ng + zg * hprev[r];
            hprev[r] = hnew;
            hs[w * 4 + r][ch] = hnew;   // same-wave LDS dep, compiler orders via lgkmcnt
            if (LAYER == 0)
                outseq[(((size_t)(t * NROWS + row)) << 6) + ch] = hnew;
        }
    }
    if (LAYER == 1) {
#pragma unroll
        for (int r = 0; r < 4; ++r)
            outseq[(((size_t)(row0 + r)) << 6) + ch] = hprev[r];
    }
}

// ---------------- final MLP ----------------
__global__ __launch_bounds__(64) void mlp_head(
    const float* __restrict__ hT, const float* __restrict__ pW1,
    const float* __restrict__ pb1, const float* __restrict__ pW2,
    const float* __restrict__ pb2, float* __restrict__ out) {
    int r = blockIdx.x, lane = threadIdx.x;
    __shared__ float hrow[64];
    __shared__ float mid[64];
    hrow[lane] = hT[((size_t)r << 6) + lane];
    __syncthreads();
    float acc = pb1[lane];
#pragma unroll
    for (int k = 0; k < 64; ++k) acc = fmaf(hrow[k], pW1[k * 64 + lane], acc);
    mid[lane] = fmaxf(acc, 0.f);
    __syncthreads();
    if (lane < 10) {
        float o = pb2[lane];
#pragma unroll
        for (int k = 0; k < 64; ++k) o = fmaf(mid[k], pW2[k * 10 + lane], o);
        out[(size_t)r * 10 + lane] = o;
    }
}

// ---------------- launch ----------------
extern "C" void kernel_launch(void* const* d_in, const int* in_sizes, int n_in,
                              void* d_out, int out_size, void* d_ws, size_t ws_size,
                              hipStream_t stream) {
    (void)in_sizes; (void)n_in; (void)out_size; (void)ws_size;
    const float* x    = (const float*)d_in[0];
    const int*   ei   = (const int*)d_in[1];
    const float* W1   = (const float*)d_in[3];
    const float* as1  = (const float*)d_in[4];
    const float* ad1  = (const float*)d_in[5];
    const float* b1   = (const float*)d_in[6];
    const float* W2   = (const float*)d_in[7];
    const float* as2  = (const float*)d_in[8];
    const float* ad2  = (const float*)d_in[9];
    const float* b2   = (const float*)d_in[10];
    const float* Wih0 = (const float*)d_in[13];
    const float* Whh0 = (const float*)d_in[14];
    const float* bih0 = (const float*)d_in[15];
    const float* bhh0 = (const float*)d_in[16];
    const float* Wih1 = (const float*)d_in[17];
    const float* Whh1 = (const float*)d_in[18];
    const float* bih1 = (const float*)d_in[19];
    const float* bhh1 = (const float*)d_in[20];
    const float* pW1  = (const float*)d_in[21];
    const float* pb1  = (const float*)d_in[22];
    const float* pW2  = (const float*)d_in[23];
    const float* pb2  = (const float*)d_in[24];
    float* out = (float*)d_out;

    // workspace layout (bytes); overlays noted
    char* ws = (char*)d_ws;
    float* hlin  = (float*)(ws + 0);           // 32,768,000  (overlay: giseq 24.58MB)
    float* giseq = hlin;
    float* asrc  = (float*)(ws + 32768000);    // 512,000     (overlay: hT 1MB spans asrc+adst)
    float* hT    = asrc;
    float* adst  = (float*)(ws + 33280000);    // 512,000
    float* gat1  = (float*)(ws + 33792000);    // 8,192,000   (overlay: h1seq)
    float* h1seq = gat1;
    float* gat2  = (float*)(ws + 41984000);    // 8,192,000
    int* counts  = (int*)(ws + 50176000);      // 128,000
    int* cursor  = (int*)(ws + 50304000);      // 128,000
    int* offs    = (int*)(ws + 50432000);      // 128,004 (padded to 128,256)
    int* csr     = (int*)(ws + 50560256);      // 2,176,000  -> total 52.7MB

    hipMemsetAsync(counts, 0, 2 * GN * sizeof(int), stream);  // counts + cursor (adjacent)

    dim3 egrid((E2 + 255) / 256, GG);
    count_edges<<<egrid, 256, 0, stream>>>(ei, counts);
    scan_offsets_pg<<<GG, 256, 0, stream>>>(counts, offs);
    scatter_edges<<<egrid, 256, 0, stream>>>(ei, offs, cursor, csr);

    gat_linear<0><<<GG * 100, 256, 0, stream>>>(x, W1, as1, ad1, hlin, asrc, adst);
    gat_edge<<<GN / 4, 256, 0, stream>>>(hlin, asrc, adst, offs, csr, b1, gat1, 1);
    gat_linear<1><<<GG * 100, 256, 0, stream>>>(gat1, W2, as2, ad2, hlin, asrc, adst);
    gat_edge<<<GN / 4, 256, 0, stream>>>(hlin, asrc, adst, offs, csr, b2, gat2, 0);

    gru_gi<0><<<3200, 192, 0, stream>>>(gat2, Wih0, bih0, giseq);
    gru_rec<0><<<500, 128, 0, stream>>>(giseq, Whh0, bhh0, h1seq);
    gru_gi<1><<<3200, 192, 0, stream>>>(h1seq, Wih1, bih1, giseq);
    gru_rec<1><<<500, 128, 0, stream>>>(giseq, Whh1, bhh1, hT);

    mlp_head<<<NROWS, 64, 0, stream>>>(hT, pW1, pb1, pW2, pb2, out);
}

// Round 9
// 432.453 us; speedup vs baseline: 1.1912x; 1.0067x over previous
//
#include <hip/hip_runtime.h>
#include <math.h>

// Problem constants
#define BB 4
#define NN 1000
#define TT 8
#define FF 64
#define HH 64
#define NHEADS 4
#define EE 16000
#define E2 17000          // EE + NN self-loops (EXACT per-graph edge total)
#define GG (BB*TT)        // 32 graphs
#define GN (GG*NN)        // 32000 (graph,node) pairs
#define NROWS (BB*NN)     // 4000 GRU rows

// ---------------- helpers ----------------
__device__ __forceinline__ float sigmoidf_(float x) {
    return 1.f / (1.f + __expf(-x));
}
__device__ __forceinline__ float tanhf_(float x) {
    x = fminf(fmaxf(x, -15.f), 15.f);
    float e = __expf(2.f * x);
    return (e - 1.f) / (e + 1.f);
}
__device__ __forceinline__ float leaky_(float x) {
    return (x > 0.f) ? x : 0.2f * x;
}

// ---------------- CSR build ----------------
__global__ void count_edges(const int* __restrict__ ei, int* __restrict__ counts) {
    int g = blockIdx.y;
    int e = blockIdx.x * 256 + threadIdx.x;
    if (e >= E2) return;
    int dst;
    if (e < EE) dst = ei[(size_t)g * 2 * EE + EE + e];
    else        dst = e - EE;   // self-loop
    atomicAdd(&counts[g * NN + dst], 1);
}

// Per-graph scan: each graph owns csr region [g*E2, (g+1)*E2); only a
// 1000-element scan per graph is needed. One 256-thread block per graph.
__global__ __launch_bounds__(256) void scan_offsets_pg(const int* __restrict__ counts,
                                                       int* __restrict__ offs) {
    __shared__ int tot[256];
    int g = blockIdx.x;
    int tid = threadIdx.x;
    int base = tid * 4;
    int c0 = 0, c1 = 0, c2 = 0, c3 = 0;
    if (base < NN) {
        int4 v = *(const int4*)(counts + (size_t)g * NN + base);  // 16B aligned (NN%4==0)
        c0 = v.x; c1 = v.y; c2 = v.z; c3 = v.w;
    }
    int s = c0 + c1 + c2 + c3;
    tot[tid] = s;
    __syncthreads();
    // Hillis-Steele inclusive scan over 256 partials
    for (int off = 1; off < 256; off <<= 1) {
        int y = (tid >= off) ? tot[tid - off] : 0;
        __syncthreads();
        tot[tid] += y;
        __syncthreads();
    }
    int run = g * E2 + tot[tid] - s;  // exclusive prefix + graph base
    if (base < NN) {
        int4 o;
        o.x = run; run += c0;
        o.y = run; run += c1;
        o.z = run; run += c2;
        o.w = run;
        *(int4*)(offs + (size_t)g * NN + base) = o;
    }
    if (g == 0 && tid == 0) offs[GN] = GG * E2;
}

__global__ void scatter_edges(const int* __restrict__ ei, const int* __restrict__ offs,
                              int* __restrict__ cursor, int* __restrict__ csr) {
    int g = blockIdx.y;
    int e = blockIdx.x * 256 + threadIdx.x;
    if (e >= E2) return;
    int src, dst;
    if (e < EE) {
        src = ei[(size_t)g * 2 * EE + e];
        dst = ei[(size_t)g * 2 * EE + EE + e];
    } else {
        src = dst = e - EE;
    }
    int i = g * NN + dst;
    int pos = offs[i] + atomicAdd(&cursor[i], 1);
    csr[pos] = src;
}

// Register pin (used by gru_gi; kept from R7 to avoid confounds there)
#define PIN64_(arr)                                        \
    _Pragma("unroll")                                      \
    for (int _pi = 0; _pi < 64; ++_pi)                     \
        asm volatile("" : "+v"((arr)[_pi]));

// ---------------- GAT linear (R8-measured config; FROZEN) ----------------
// v2 body: wcol strided loads, wave-uniform scalar x loads, ROWS=10.
// hlin layout: [node][chan][head] (head fastest, float4 per chan)
// MODE 0: input is x [B,N,T,F] gathered per graph g=(b,t).  MODE 1: input [G,N,F] contiguous.
template <int MODE>
__global__ __launch_bounds__(256) void gat_linear(
    const float* __restrict__ in, const float* __restrict__ W,
    const float* __restrict__ att_s, const float* __restrict__ att_d,
    float* __restrict__ hlin, float* __restrict__ asrc, float* __restrict__ adst) {
    const int ROWS = 10;
    const int CH = NN / ROWS;  // 100 -> 3200 blocks
    int g = blockIdx.x / CH;
    int n0 = (blockIdx.x % CH) * ROWS;
    int tid = threadIdx.x;
    // W column into registers: W[f][tid]
    float wcol[FF];
#pragma unroll
    for (int f = 0; f < FF; ++f) wcol[f] = W[f * 256 + tid];
    int head = tid >> 6, lane = tid & 63;
    float as = att_s[head * HH + lane];
    float ad = att_d[head * HH + lane];
    int b = g / TT, t = g % TT;
    for (int r = 0; r < ROWS; ++r) {
        int n = n0 + r;
        const float* xrow;
        if (MODE == 0) xrow = in + (((size_t)(b * NN + n) * TT + t) * FF);
        else           xrow = in + ((size_t)(g * NN + n) * FF);
        float acc = 0.f;
#pragma unroll
        for (int f = 0; f < FF; ++f) acc = fmaf(xrow[f], wcol[f], acc);
        // transposed store: [node][chan=lane][head]
        hlin[((size_t)(g * NN + n) << 8) + (lane << 2) + head] = acc;
        float s1 = acc * as, s2 = acc * ad;
#pragma unroll
        for (int off = 32; off; off >>= 1) {
            s1 += __shfl_xor(s1, off, 64);
            s2 += __shfl_xor(s2, off, 64);
        }
        if (lane == 0) {
            asrc[(size_t)(g * NN + n) * NHEADS + head] = s1;
            adst[(size_t)(g * NN + n) * NHEADS + head] = s2;
        }
    }
}

// ---------------- GAT edge softmax + aggregation (v3: 8-way MLP phase B) ----------------
// One wave per destination node. Phase A computes per-edge weights into LDS
// (zero-filled beyond deg). Phase B rounds the edge count up to a multiple of
// 8 (padded edges: p=0, src=0 -> harmless) and issues 8 independent 1KB
// gathers per batch: MLP 1 -> 8 (R8: serial loop was latency-bound, L2 at
// 36% of ceiling, VALUBusy 33%).
__global__ __launch_bounds__(256) void gat_edge(
    const float* __restrict__ hlin, const float* __restrict__ asrc,
    const float* __restrict__ adst, const int* __restrict__ offs,
    const int* __restrict__ csr, const float* __restrict__ bias,
    float* __restrict__ out, int do_relu) {
    __shared__ float pbuf[4][64][4];   // [wave][edge-in-chunk][head]
    __shared__ int   sbuf[4][64];
    __shared__ int   degs[4];
    int tid = threadIdx.x;
    int lane = tid & 63, w = tid >> 6;
    // XCD swizzle: graph g -> XCD g%8 (consecutive blockIdx round-robins XCDs)
    int B = blockIdx.x;
    int x = B & 7, j = B >> 3;             // j in 0..999
    int graph = x + 8 * (j / 250);
    int node = graph * NN + ((j % 250) << 2) + w;
    int beg = offs[node], end = offs[node + 1];
    int deg = end - beg;
    if (lane == 0) degs[w] = deg;
    __syncthreads();
    int maxdeg = max(max(degs[0], degs[1]), max(degs[2], degs[3]));
    int nchunk = (maxdeg + 63) >> 6;

    float4 ad = *(const float4*)(adst + (size_t)node * 4);
    const float* asrc_g = asrc + (size_t)graph * NN * 4;
    const float* hg = hlin + ((size_t)graph * NN << 8);

    float4 acc = make_float4(0.f, 0.f, 0.f, 0.f);
    float4 ssum = make_float4(0.f, 0.f, 0.f, 0.f);
    for (int c = 0; c < nchunk; ++c) {
        int e0 = beg + (c << 6);
        int myedge = e0 + lane;
        float4 p = make_float4(0.f, 0.f, 0.f, 0.f);
        int src = 0;
        if (myedge < end) {
            src = csr[myedge];
            float4 a = *(const float4*)(asrc_g + (size_t)src * 4);
            p.x = __expf(leaky_(a.x + ad.x));
            p.y = __expf(leaky_(a.y + ad.y));
            p.z = __expf(leaky_(a.z + ad.z));
            p.w = __expf(leaky_(a.w + ad.w));
        }
        // butterfly sum of this chunk's weights
        float4 t = p;
#pragma unroll
        for (int off = 1; off < 64; off <<= 1) {
            t.x += __shfl_xor(t.x, off, 64);
            t.y += __shfl_xor(t.y, off, 64);
            t.z += __shfl_xor(t.z, off, 64);
            t.w += __shfl_xor(t.w, off, 64);
        }
        ssum.x += t.x; ssum.y += t.y; ssum.z += t.z; ssum.w += t.w;
        *(float4*)&pbuf[w][lane][0] = p;
        sbuf[w][lane] = src;
        __syncthreads();
        int cnt = end - e0;
        if (cnt > 64) cnt = 64;
        int cnt8 = (cnt + 7) & ~7;         // pad to x8: pbuf/sbuf zero-filled
        for (int e = 0; e < cnt8; e += 8) {
            float4 p0 = *(const float4*)&pbuf[w][e + 0][0];
            float4 p1 = *(const float4*)&pbuf[w][e + 1][0];
            float4 p2 = *(const float4*)&pbuf[w][e + 2][0];
            float4 p3 = *(const float4*)&pbuf[w][e + 3][0];
            float4 p4 = *(const float4*)&pbuf[w][e + 4][0];
            float4 p5 = *(const float4*)&pbuf[w][e + 5][0];
            float4 p6 = *(const float4*)&pbuf[w][e + 6][0];
            float4 p7 = *(const float4*)&pbuf[w][e + 7][0];
            int s0 = sbuf[w][e + 0], s1 = sbuf[w][e + 1];
            int s2 = sbuf[w][e + 2], s3 = sbuf[w][e + 3];
            int s4 = sbuf[w][e + 4], s5 = sbuf[w][e + 5];
            int s6 = sbuf[w][e + 6], s7 = sbuf[w][e + 7];
            int lo = lane << 2;
            float4 h0 = *(const float4*)(hg + (((size_t)s0) << 8) + lo);
            float4 h1 = *(const float4*)(hg + (((size_t)s1) << 8) + lo);
            float4 h2 = *(const float4*)(hg + (((size_t)s2) << 8) + lo);
            float4 h3 = *(const float4*)(hg + (((size_t)s3) << 8) + lo);
            float4 h4 = *(const float4*)(hg + (((size_t)s4) << 8) + lo);
            float4 h5 = *(const float4*)(hg + (((size_t)s5) << 8) + lo);
            float4 h6 = *(const float4*)(hg + (((size_t)s6) << 8) + lo);
            float4 h7 = *(const float4*)(hg + (((size_t)s7) << 8) + lo);
            acc.x = fmaf(p0.x, h0.x, acc.x); acc.y = fmaf(p0.y, h0.y, acc.y);
            acc.z = fmaf(p0.z, h0.z, acc.z); acc.w = fmaf(p0.w, h0.w, acc.w);
            acc.x = fmaf(p1.x, h1.x, acc.x); acc.y = fmaf(p1.y, h1.y, acc.y);
            acc.z = fmaf(p1.z, h1.z, acc.z); acc.w = fmaf(p1.w, h1.w, acc.w);
            acc.x = fmaf(p2.x, h2.x, acc.x); acc.y = fmaf(p2.y, h2.y, acc.y);
            acc.z = fmaf(p2.z, h2.z, acc.z); acc.w = fmaf(p2.w, h2.w, acc.w);
            acc.x = fmaf(p3.x, h3.x, acc.x); acc.y = fmaf(p3.y, h3.y, acc.y);
            acc.z = fmaf(p3.z, h3.z, acc.z); acc.w = fmaf(p3.w, h3.w, acc.w);
            acc.x = fmaf(p4.x, h4.x, acc.x); acc.y = fmaf(p4.y, h4.y, acc.y);
            acc.z = fmaf(p4.z, h4.z, acc.z); acc.w = fmaf(p4.w, h4.w, acc.w);
            acc.x = fmaf(p5.x, h5.x, acc.x); acc.y = fmaf(p5.y, h5.y, acc.y);
            acc.z = fmaf(p5.z, h5.z, acc.z); acc.w = fmaf(p5.w, h5.w, acc.w);
            acc.x = fmaf(p6.x, h6.x, acc.x); acc.y = fmaf(p6.y, h6.y, acc.y);
            acc.z = fmaf(p6.z, h6.z, acc.z); acc.w = fmaf(p6.w, h6.w, acc.w);
            acc.x = fmaf(p7.x, h7.x, acc.x); acc.y = fmaf(p7.y, h7.y, acc.y);
            acc.z = fmaf(p7.z, h7.z, acc.z); acc.w = fmaf(p7.w, h7.w, acc.w);
        }
        __syncthreads();
    }
    float o = 0.25f * (acc.x / ssum.x + acc.y / ssum.y + acc.z / ssum.z + acc.w / ssum.w)
            + bias[lane];
    if (do_relu) o = fmaxf(o, 0.f);
    out[((size_t)node << 6) + lane] = o;
}

// ---------------- GRU input-side GEMM: giseq[t][r][192] = bih + x_t[r] @ Wih^T ----------------
// v3: W pinned register-resident (asm), launch_bounds(192,4), 3200 blocks,
// 2-row ILP pairs, float4 x loads.
// MODE 0: input gat2out [G][N][64] gathered (g=b*T+t, row=(b,n)).  MODE 1: input [T][4000][64] flat.
template <int MODE>
__global__ __launch_bounds__(192, 4) void gru_gi(
    const float* __restrict__ in, const float* __restrict__ Wih,
    const float* __restrict__ bih, float* __restrict__ giseq) {
    const int ROWS = 10;  // 3200 blocks * 10 = 32000 (t,row) pairs
    int j = threadIdx.x;  // 0..191
    float wrow[64];
#pragma unroll
    for (int f4 = 0; f4 < 16; ++f4) {
        float4 w = *(const float4*)(Wih + (size_t)j * 64 + f4 * 4);
        wrow[4 * f4 + 0] = w.x; wrow[4 * f4 + 1] = w.y;
        wrow[4 * f4 + 2] = w.z; wrow[4 * f4 + 3] = w.w;
    }
    PIN64_(wrow)
    float bj = bih[j];
    int q0 = blockIdx.x * ROWS;
    int t = q0 / NROWS;            // constant per block (NROWS % ROWS == 0)
    int r0 = q0 - t * NROWS;
    for (int rr = 0; rr < ROWS; rr += 2) {
        const float *xa, *xb;
        if (MODE == 0) {
            int ra = r0 + rr, rb = ra + 1;
            int ba = ra / NN, na = ra - ba * NN;
            int bb2 = rb / NN, nb = rb - bb2 * NN;
            xa = in + (((size_t)(ba * TT + t) * NN + na) << 6);
            xb = in + (((size_t)(bb2 * TT + t) * NN + nb) << 6);
        } else {
            xa = in + ((size_t)(q0 + rr) << 6);
            xb = xa + 64;
        }
        float acca = bj, accb = bj;
#pragma unroll
        for (int f4 = 0; f4 < 16; ++f4) {
            float4 a4 = *(const float4*)(xa + f4 * 4);
            float4 b4 = *(const float4*)(xb + f4 * 4);
            acca = fmaf(a4.x, wrow[4 * f4 + 0], acca);
            acca = fmaf(a4.y, wrow[4 * f4 + 1], acca);
            acca = fmaf(a4.z, wrow[4 * f4 + 2], acca);
            acca = fmaf(a4.w, wrow[4 * f4 + 3], acca);
            accb = fmaf(b4.x, wrow[4 * f4 + 0], accb);
            accb = fmaf(b4.y, wrow[4 * f4 + 1], accb);
            accb = fmaf(b4.z, wrow[4 * f4 + 2], accb);
            accb = fmaf(b4.w, wrow[4 * f4 + 3], accb);
        }
        giseq[(size_t)(q0 + rr) * 192 + j] = acca;
        giseq[(size_t)(q0 + rr + 1) * 192 + j] = accb;
    }
}

// ---------------- GRU recurrence v2 (Whh side only; gi precomputed) ----------------
// Thread ch owns the full gate triplet: Whh rows {ch, 64+ch, 128+ch} in 192 VGPRs.
// h-state in LDS, wave-private (wave w owns rows w*4..w*4+3) -> ZERO barriers.
// h reads are wave-uniform ds_read_b128 broadcasts (16 per row).
// LAYER 0: outseq = h1seq [T][4000][64] (store every t). LAYER 1: outseq = hT [4000][64].
template <int LAYER>
__global__ __launch_bounds__(128) void gru_rec(
    const float* __restrict__ giseq, const float* __restrict__ Whh,
    const float* __restrict__ bhh, float* __restrict__ outseq) {
    __shared__ float hs[8][64];       // 2 waves * 4 rows, wave-private regions
    int tid = threadIdx.x;
    int ch = tid & 63, w = tid >> 6;  // w in {0,1}
    float wr[64], wz[64], wn[64];
#pragma unroll
    for (int k4 = 0; k4 < 16; ++k4) {
        float4 a = *(const float4*)(Whh + (size_t)ch * 64 + k4 * 4);
        float4 b = *(const float4*)(Whh + (size_t)(64 + ch) * 64 + k4 * 4);
        float4 c = *(const float4*)(Whh + (size_t)(128 + ch) * 64 + k4 * 4);
        wr[4*k4+0] = a.x; wr[4*k4+1] = a.y; wr[4*k4+2] = a.z; wr[4*k4+3] = a.w;
        wz[4*k4+0] = b.x; wz[4*k4+1] = b.y; wz[4*k4+2] = b.z; wz[4*k4+3] = b.w;
        wn[4*k4+0] = c.x; wn[4*k4+1] = c.y; wn[4*k4+2] = c.z; wn[4*k4+3] = c.w;
    }
    float br = bhh[ch], bz = bhh[64 + ch], bn = bhh[128 + ch];
    int row0 = blockIdx.x * 8 + w * 4;
    float hprev[4];
#pragma unroll
    for (int r = 0; r < 4; ++r) { hs[w * 4 + r][ch] = 0.f; hprev[r] = 0.f; }

    for (int t = 0; t < TT; ++t) {
#pragma unroll
        for (int r = 0; r < 4; ++r) {
            int row = row0 + r;
            const float* gp = giseq + ((size_t)(t * NROWS + row)) * 192;
            float gir = gp[ch], giz = gp[64 + ch], gin = gp[128 + ch];
            float ar = br, az = bz, an = bn;
#pragma unroll
            for (int k4 = 0; k4 < 16; ++k4) {
                float4 h4 = *(const float4*)&hs[w * 4 + r][k4 * 4];  // broadcast
                ar = fmaf(h4.x, wr[4*k4+0], ar); ar = fmaf(h4.y, wr[4*k4+1], ar);
                ar = fmaf(h4.z, wr[4*k4+2], ar); ar = fmaf(h4.w, wr[4*k4+3], ar);
                az = fmaf(h4.x, wz[4*k4+0], az); az = fmaf(h4.y, wz[4*k4+1], az);
                az = fmaf(h4.z, wz[4*k4+2], az); az = fmaf(h4.w, wz[4*k4+3], az);
                an = fmaf(h4.x, wn[4*k4+0], an); an = fmaf(h4.y, wn[4*k4+1], an);
                an = fmaf(h4.z, wn[4*k4+2], an); an = fmaf(h4.w, wn[4*k4+3], an);
            }
            float rg = sigmoidf_(gir + ar);
            float zg = sigmoidf_(giz + az);
            float ng = tanhf_(gin + rg * an);
            float hnew = (1.f - zg) * ng + zg * hprev[r];
            hprev[r] = hnew;
            hs[w * 4 + r][ch] = hnew;   // same-wave LDS dep, compiler orders via lgkmcnt
            if (LAYER == 0)
                outseq[(((size_t)(t * NROWS + row)) << 6) + ch] = hnew;
        }
    }
    if (LAYER == 1) {
#pragma unroll
        for (int r = 0; r < 4; ++r)
            outseq[(((size_t)(row0 + r)) << 6) + ch] = hprev[r];
    }
}

// ---------------- final MLP ----------------
__global__ __launch_bounds__(64) void mlp_head(
    const float* __restrict__ hT, const float* __restrict__ pW1,
    const float* __restrict__ pb1, const float* __restrict__ pW2,
    const float* __restrict__ pb2, float* __restrict__ out) {
    int r = blockIdx.x, lane = threadIdx.x;
    __shared__ float hrow[64];
    __shared__ float mid[64];
    hrow[lane] = hT[((size_t)r << 6) + lane];
    __syncthreads();
    float acc = pb1[lane];
#pragma unroll
    for (int k = 0; k < 64; ++k) acc = fmaf(hrow[k], pW1[k * 64 + lane], acc);
    mid[lane] = fmaxf(acc, 0.f);
    __syncthreads();
    if (lane < 10) {
        float o = pb2[lane];
#pragma unroll
        for (int k = 0; k < 64; ++k) o = fmaf(mid[k], pW2[k * 10 + lane], o);
        out[(size_t)r * 10 + lane] = o;
    }
}

// ---------------- launch ----------------
extern "C" void kernel_launch(void* const* d_in, const int* in_sizes, int n_in,
                              void* d_out, int out_size, void* d_ws, size_t ws_size,
                              hipStream_t stream) {
    (void)in_sizes; (void)n_in; (void)out_size; (void)ws_size;
    const float* x    = (const float*)d_in[0];
    const int*   ei   = (const int*)d_in[1];
    const float* W1   = (const float*)d_in[3];
    const float* as1  = (const float*)d_in[4];
    const float* ad1  = (const float*)d_in[5];
    const float* b1   = (const float*)d_in[6];
    const float* W2   = (const float*)d_in[7];
    const float* as2  = (const float*)d_in[8];
    const float* ad2  = (const float*)d_in[9];
    const float* b2   = (const float*)d_in[10];
    const float* Wih0 = (const float*)d_in[13];
    const float* Whh0 = (const float*)d_in[14];
    const float* bih0 = (const float*)d_in[15];
    const float* bhh0 = (const float*)d_in[16];
    const float* Wih1 = (const float*)d_in[17];
    const float* Whh1 = (const float*)d_in[18];
    const float* bih1 = (const float*)d_in[19];
    const float* bhh1 = (const float*)d_in[20];
    const float* pW1  = (const float*)d_in[21];
    const float* pb1  = (const float*)d_in[22];
    const float* pW2  = (const float*)d_in[23];
    const float* pb2  = (const float*)d_in[24];
    float* out = (float*)d_out;

    // workspace layout (bytes); overlays noted
    char* ws = (char*)d_ws;
    float* hlin  = (float*)(ws + 0);           // 32,768,000  (overlay: giseq 24.58MB)
    float* giseq = hlin;
    float* asrc  = (float*)(ws + 32768000);    // 512,000     (overlay: hT 1MB spans asrc+adst)
    float* hT    = asrc;
    float* adst  = (float*)(ws + 33280000);    // 512,000
    float* gat1  = (float*)(ws + 33792000);    // 8,192,000   (overlay: h1seq)
    float* h1seq = gat1;
    float* gat2  = (float*)(ws + 41984000);    // 8,192,000
    int* counts  = (int*)(ws + 50176000);      // 128,000
    int* cursor  = (int*)(ws + 50304000);      // 128,000
    int* offs    = (int*)(ws + 50432000);      // 128,004 (padded to 128,256)
    int* csr     = (int*)(ws + 50560256);      // 2,176,000  -> total 52.7MB

    hipMemsetAsync(counts, 0, 2 * GN * sizeof(int), stream);  // counts + cursor (adjacent)

    dim3 egrid((E2 + 255) / 256, GG);
    count_edges<<<egrid, 256, 0, stream>>>(ei, counts);
    scan_offsets_pg<<<GG, 256, 0, stream>>>(counts, offs);
    scatter_edges<<<egrid, 256, 0, stream>>>(ei, offs, cursor, csr);

    gat_linear<0><<<GG * 100, 256, 0, stream>>>(x, W1, as1, ad1, hlin, asrc, adst);
    gat_edge<<<GN / 4, 256, 0, stream>>>(hlin, asrc, adst, offs, csr, b1, gat1, 1);
    gat_linear<1><<<GG * 100, 256, 0, stream>>>(gat1, W2, as2, ad2, hlin, asrc, adst);
    gat_edge<<<GN / 4, 256, 0, stream>>>(hlin, asrc, adst, offs, csr, b2, gat2, 0);

    gru_gi<0><<<3200, 192, 0, stream>>>(gat2, Wih0, bih0, giseq);
    gru_rec<0><<<500, 128, 0, stream>>>(giseq, Whh0, bhh0, h1seq);
    gru_gi<1><<<3200, 192, 0, stream>>>(h1seq, Wih1, bih1, giseq);
    gru_rec<1><<<500, 128, 0, stream>>>(giseq, Whh1, bhh1, hT);

    mlp_head<<<NROWS, 64, 0, stream>>>(hT, pW1, pb1, pW2, pb2, out);
}